// Round 7
// baseline (323.063 us; speedup 1.0000x reference)
//
#include <hip/hip_runtime.h>

// SEAFLOW3DP cascaded convex upsampling: x16 -> x8 -> x4 -> x2 -> x1.
// R7: two kernels.
//  1) fused123 (R5, proven): stages 1-3 tile-recompute in LDS -> flowC/dzC (ws).
//  2) up4_rows: stage 4 restructured for SEQUENTIAL HBM reads. One block per
//     coarse row; the 18 mask2 channel-rows needed for each sy half are staged
//     into LDS with 1KB-contiguous wave loads (exp applied during staging),
//     then consumed as a (free) strided LDS gather. Field taps sit in regs.
// Theory: the 36-plane strided gather (planes 786KB apart, 128B runs) thrashes
// DRAM row buffers -> all prior variants plateau at 1.6-2.2 TB/s regardless of
// occupancy. Sequential staging should restore >4 TB/s.
//
// Mask layout (N,36,Hc,Wc), channel c = k*4 + sy*2 + sx, k = kh*3 + kw.
// Zero-padded taps contribute 0 to the numerator but keep their softmax
// weight in the denominator. Flow premul=2/stage (folded into norm); dz=1.

#define NB 4  // batch

// ---------------- fused stages 1-3: 48x64 inputs -> flowC/dzC 384x512 ----
__global__ __launch_bounds__(256, 4) void fused123(
    const float* __restrict__ flow16, const float* __restrict__ dz16,
    const float* __restrict__ mask16, const float* __restrict__ mask8,
    const float* __restrict__ mask4,
    float* __restrict__ flowC, float* __restrict__ dzC)
{
    constexpr int H0 = 48,  W0 = 64,  HW0 = H0 * W0;
    constexpr int H1 = 96,  W1 = 128, HW1 = H1 * W1;
    constexpr int H2 = 192, W2 = 256, HW2 = H2 * W2;
    constexpr int H3 = 384, W3 = 512, HW3 = H3 * W3;

    __shared__ float sA[3][12][12];  // flowA region rows A1h-2..A1h+9
    __shared__ float sB[3][18][18];  // flowB region rows A2h-1..A2h+16

    int bid = blockIdx.x;
    int n  = bid / 192;
    int tt = bid % 192;
    int TR = tt / 16, TC = tt % 16;     // 12x16 tiles of 32x32 over 384x512
    int A2h = TR * 16, A2w = TC * 16;   // coarse base at 192x256
    int A1h = A2h / 2, A1w = A2w / 2;   // coarse base at 96x128

    const float* f16 = flow16 + (size_t)n * 2 * HW0;
    const float* d16 = dz16   + (size_t)n * HW0;
    const float* m16 = mask16 + (size_t)n * 36 * HW0;
    const float* m8  = mask8  + (size_t)n * 36 * HW1;
    const float* m4  = mask4  + (size_t)n * 36 * HW2;

    int tid = threadIdx.x;

    // ---- phase 1: flowA 12x12 halo region (stage 1) ----
    if (tid < 144) {
        int i = tid / 12, j = tid % 12;
        int gh = A1h - 2 + i, gw = A1w - 2 + j;   // global 96x128 coords
        float ox = 0.f, oy = 0.f, oz = 0.f;
        if ((unsigned)gh < (unsigned)H1 && (unsigned)gw < (unsigned)W1) {
            int ch = gh >> 1, cw = gw >> 1;       // 48x64 coords
            int q = (gh & 1) * 2 + (gw & 1);
            const float* mb = m16 + (size_t)q * HW0 + ch * W0 + cw;
            float e[9];
#pragma unroll
            for (int k = 0; k < 9; ++k) e[k] = __expf(mb[(size_t)(k * 4) * HW0]);
            float s = 0.f, ax = 0.f, ay = 0.f, az = 0.f;
#pragma unroll
            for (int kh = 0; kh < 3; ++kh) {
                int hh = ch + kh - 1;
                bool vh = (unsigned)hh < (unsigned)H0;
                int hcl = min(max(hh, 0), H0 - 1);
#pragma unroll
                for (int kw = 0; kw < 3; ++kw) {
                    int ww = cw + kw - 1;
                    bool v = vh && ((unsigned)ww < (unsigned)W0);
                    int wcl = min(max(ww, 0), W0 - 1);
                    int o = hcl * W0 + wcl;
                    float w = e[kh * 3 + kw];
                    s += w;
                    ax += w * (v ? f16[o] : 0.f);
                    ay += w * (v ? f16[HW0 + o] : 0.f);
                    az += w * (v ? d16[o] : 0.f);
                }
            }
            float inv = __builtin_amdgcn_rcpf(s);
            ox = 2.f * ax * inv; oy = 2.f * ay * inv; oz = az * inv;
        }
        sA[0][i][j] = ox; sA[1][i][j] = oy; sA[2][i][j] = oz;
    }
    __syncthreads();

    // ---- phase 2: flowB 18x18 halo region (stage 2; taps from sA) ----
    for (int p = tid; p < 324; p += 256) {
        int i = p / 18, j = p % 18;
        int gh = A2h - 1 + i, gw = A2w - 1 + j;   // global 192x256 coords
        float ox = 0.f, oy = 0.f, oz = 0.f;
        if ((unsigned)gh < (unsigned)H2 && (unsigned)gw < (unsigned)W2) {
            int ch = gh >> 1, cw = gw >> 1;       // 96x128 coords
            int q = (gh & 1) * 2 + (gw & 1);
            const float* mb = m8 + (size_t)q * HW1 + ch * W1 + cw;
            float e[9];
#pragma unroll
            for (int k = 0; k < 9; ++k) e[k] = __expf(mb[(size_t)(k * 4) * HW1]);
            int li = ch - A1h + 2, lj = cw - A1w + 2;  // sA local center
            float s = 0.f, ax = 0.f, ay = 0.f, az = 0.f;
#pragma unroll
            for (int kh = 0; kh < 3; ++kh)
#pragma unroll
                for (int kw = 0; kw < 3; ++kw) {
                    float w = e[kh * 3 + kw];
                    s += w;
                    ax += w * sA[0][li + kh - 1][lj + kw - 1];
                    ay += w * sA[1][li + kh - 1][lj + kw - 1];
                    az += w * sA[2][li + kh - 1][lj + kw - 1];
                }
            float inv = __builtin_amdgcn_rcpf(s);
            ox = 2.f * ax * inv; oy = 2.f * ay * inv; oz = az * inv;
        }
        sB[0][i][j] = ox; sB[1][i][j] = oy; sB[2][i][j] = oz;
    }
    __syncthreads();

    // ---- phase 3: flowC 32x32 tile, 4 horizontally-consecutive px/thread ----
    int ph = tid / 8;          // tile row 0..31
    int j4 = tid % 8;          // col group; fine cols 4*j4 .. 4*j4+3
    int sy = ph & 1;
    int crow = A2h + (ph >> 1);          // mask4/flowB coarse row (192x256)
    int ccol = A2w + 2 * j4;             // left coarse col of the pair

    const float* mb = m4 + (size_t)(sy * 2) * HW2 + crow * W2 + ccol;
    float2 e0[9], e1[9];  // sx=0 / sx=1 channels; .x=left coarse col, .y=right
#pragma unroll
    for (int k = 0; k < 9; ++k) {
        e0[k] = *(const float2*)(mb + (size_t)(k * 4) * HW2);
        e1[k] = *(const float2*)(mb + (size_t)(k * 4 + 1) * HW2);
    }
#pragma unroll
    for (int k = 0; k < 9; ++k) {
        e0[k].x = __expf(e0[k].x); e0[k].y = __expf(e0[k].y);
        e1[k].x = __expf(e1[k].x); e1[k].y = __expf(e1[k].y);
    }

    float s[4] = {0, 0, 0, 0}, ax[4] = {0, 0, 0, 0},
          ay[4] = {0, 0, 0, 0}, az[4] = {0, 0, 0, 0};
    int lr = ph >> 1;          // sB local row base
    int lc = 2 * j4;           // sB local col base
#pragma unroll
    for (int k = 0; k < 9; ++k) {
        int kh = k / 3, kw = k % 3;
        float tl0 = sB[0][lr + kh][lc + kw],     tl1 = sB[1][lr + kh][lc + kw],
              tl2 = sB[2][lr + kh][lc + kw];
        float tr0 = sB[0][lr + kh][lc + kw + 1], tr1 = sB[1][lr + kh][lc + kw + 1],
              tr2 = sB[2][lr + kh][lc + kw + 1];
        float w0 = e0[k].x, w1 = e1[k].x, w2 = e0[k].y, w3 = e1[k].y;
        s[0] += w0; ax[0] += w0 * tl0; ay[0] += w0 * tl1; az[0] += w0 * tl2;
        s[1] += w1; ax[1] += w1 * tl0; ay[1] += w1 * tl1; az[1] += w1 * tl2;
        s[2] += w2; ax[2] += w2 * tr0; ay[2] += w2 * tr1; az[2] += w2 * tr2;
        s[3] += w3; ax[3] += w3 * tr0; ay[3] += w3 * tr1; az[3] += w3 * tr2;
    }
    float i0 = __builtin_amdgcn_rcpf(s[0]);
    float i1 = __builtin_amdgcn_rcpf(s[1]);
    float i2 = __builtin_amdgcn_rcpf(s[2]);
    float i3 = __builtin_amdgcn_rcpf(s[3]);

    size_t ro = (size_t)(TR * 32 + ph) * W3 + (TC * 32 + 4 * j4);
    float* fx = flowC + (size_t)n * 2 * HW3 + ro;
    float* fz = dzC   + (size_t)n * HW3 + ro;
    float4 vx = {2.f * ax[0] * i0, 2.f * ax[1] * i1, 2.f * ax[2] * i2, 2.f * ax[3] * i3};
    float4 vy = {2.f * ay[0] * i0, 2.f * ay[1] * i1, 2.f * ay[2] * i2, 2.f * ay[3] * i3};
    float4 vz = {az[0] * i0, az[1] * i1, az[2] * i2, az[3] * i3};
    *(float4*)(fx)       = vx;
    *(float4*)(fx + HW3) = vy;
    *(float4*)(fz)       = vz;
}

// ---------------- stage 4: one block per coarse row, sequential staging ----
__global__ __launch_bounds__(256, 4) void up4_rows(
    const float* __restrict__ flowC, const float* __restrict__ dzC,
    const float* __restrict__ mask2, float* __restrict__ out)
{
    constexpr int H = 384, W = 512;
    constexpr int HW = H * W;
    constexpr int W4 = 1024, HW4 = 768 * 1024;

    __shared__ float sm[18 * 512];  // 36 KB: exp'd mask rows for one sy half

    int bid = blockIdx.x;
    int n  = bid / H;
    int hc = bid % H;
    int tid = threadIdx.x;

    // ---- field taps into registers, shared by both sy phases ----
    const float* fx = flowC + (size_t)n * 2 * HW;
    const float* fy = fx + HW;
    const float* fz = dzC + (size_t)n * HW;
    float tp[2][3][3][3];  // [wi][ch][kh][kw], wi: wc = tid + 256*wi
#pragma unroll
    for (int kh = 0; kh < 3; ++kh) {
        int hh = hc + kh - 1;
        bool vh = (unsigned)hh < (unsigned)H;
        int hr = min(max(hh, 0), H - 1);
        const float* rx = fx + (size_t)hr * W;
        const float* ry = fy + (size_t)hr * W;
        const float* rz = fz + (size_t)hr * W;
#pragma unroll
        for (int wi = 0; wi < 2; ++wi) {
            int wc = tid + 256 * wi;
#pragma unroll
            for (int kw = 0; kw < 3; ++kw) {
                int ww = wc + kw - 1;
                bool v = vh && ((unsigned)ww < (unsigned)W);
                int wr = min(max(ww, 0), W - 1);
                tp[wi][0][kh][kw] = v ? rx[wr] : 0.f;
                tp[wi][1][kh][kw] = v ? ry[wr] : 0.f;
                tp[wi][2][kh][kw] = v ? rz[wr] : 0.f;
            }
        }
    }

    const float* m2 = mask2 + (size_t)n * 36 * HW + (size_t)hc * W;

#pragma unroll 1
    for (int sy = 0; sy < 2; ++sy) {
        if (sy) __syncthreads();  // sm reads of the previous phase must finish

        // ---- stage 18 channel-rows, 1KB-contiguous per wave-instruction ----
        // flat float4 index i = tid + 256*r: cc = i/128 (channel slot),
        // pos = i%128 (float4 within the 512-float row).
#pragma unroll
        for (int r = 0; r < 9; ++r) {
            int i = tid + 256 * r;
            int cc = i >> 7, pos = i & 127;
            int k = cc >> 1, sx = cc & 1;
            const float* src = m2 + (size_t)(k * 4 + sy * 2 + sx) * HW + pos * 4;
            float4 v = *(const float4*)src;
            v.x = __expf(v.x); v.y = __expf(v.y);
            v.z = __expf(v.z); v.w = __expf(v.w);
            *(float4*)(&sm[cc * 512 + pos * 4]) = v;
        }
        __syncthreads();

        // ---- compute fine row 2*hc+sy: thread covers wc = tid, tid+256 ----
        float* ob = out + (size_t)n * 3 * HW4 + (size_t)(2 * hc + sy) * W4;
#pragma unroll
        for (int wi = 0; wi < 2; ++wi) {
            int wc = tid + 256 * wi;
            float2 vx, vy, vz;
#pragma unroll
            for (int sx = 0; sx < 2; ++sx) {
                float s = 0.f, ax = 0.f, ay = 0.f, az = 0.f;
#pragma unroll
                for (int k = 0; k < 9; ++k) {
                    float w = sm[(k * 2 + sx) * 512 + wc];
                    s  += w;
                    ax += w * tp[wi][0][k / 3][k % 3];
                    ay += w * tp[wi][1][k / 3][k % 3];
                    az += w * tp[wi][2][k / 3][k % 3];
                }
                float inv = __builtin_amdgcn_rcpf(s);
                float fs = 2.0f * inv;
                if (sx == 0) { vx.x = ax * fs; vy.x = ay * fs; vz.x = az * inv; }
                else         { vx.y = ax * fs; vy.y = ay * fs; vz.y = az * inv; }
            }
            *(float2*)(ob + 2 * wc)           = vx;  // flow ch0
            *(float2*)(ob + HW4 + 2 * wc)     = vy;  // flow ch1
            *(float2*)(ob + 2 * HW4 + 2 * wc) = vz;  // dz
        }
    }
}

extern "C" void kernel_launch(void* const* d_in, const int* in_sizes, int n_in,
                              void* d_out, int out_size, void* d_ws, size_t ws_size,
                              hipStream_t stream) {
    const float* flow16 = (const float*)d_in[0];  // (4,2,48,64)
    const float* dz16   = (const float*)d_in[1];  // (4,1,48,64)
    const float* mask16 = (const float*)d_in[2];  // (4,36,48,64)
    const float* mask8  = (const float*)d_in[3];  // (4,36,96,128)
    const float* mask4  = (const float*)d_in[4];  // (4,36,192,256)
    const float* mask2  = (const float*)d_in[5];  // (4,36,384,512)

    float* ws = (float*)d_ws;
    float* flowC = ws;                             // 4*2*384*512
    float* dzC   = flowC + 4 * 2 * 384 * 512;      // 4*1*384*512
    float* out = (float*)d_out;                    // (4,3,768,1024)

    // stages 1-3 fused: 768 blocks (4 batches x 12x16 tiles of 32x32)
    hipLaunchKernelGGL(fused123, dim3(NB * 192), dim3(256), 0, stream,
                       flow16, dz16, mask16, mask8, mask4, flowC, dzC);
    // stage 4: one block per coarse row (4*384 = 1536 blocks)
    hipLaunchKernelGGL(up4_rows, dim3(NB * 384), dim3(256), 0, stream,
                       flowC, dzC, mask2, out);
}